// Round 12
// baseline (385.344 us; speedup 1.0000x reference)
//
#include <hip/hip_runtime.h>

// SelfAttention (B=4, T=1024, C=1024, H=16, HD=64). fp32 in / fp32 out.
// R12 = R9 flash structure (best: 72.5us) + R10's conflict-free layouts:
//  - staging loads issued BEFORE S1 into short-lived regs (overlap barrier,
//    no cross-phase liveness -> no spills; R11's 244MB scratch bomb avoided)
//  - ds_write_b128 into XOR-chunk-swizzled rows (conflict-free frag reads)
//  - Ps skew stride 68 (2-way free), probs aliased into Es rows [0,64)
//  - no launch_bounds min-waves hint (R11's spill trigger)
// ws (50 MiB): q(0) k(1) vT(2) vtmp/y16(3) x16(4) WaT WpT E16.

typedef __bf16 bf16x8 __attribute__((ext_vector_type(8)));
typedef float f32x4 __attribute__((ext_vector_type(4)));
typedef unsigned short ushort_t;

#define T_SEQ 1024
#define NHEAD 16
#define HDIM 64
#define PLANE 4194304
#define C1 0.1803368801f   // 0.125 * log2(e)

__device__ __forceinline__ float bf2f(ushort_t h) {
    unsigned int u = ((unsigned int)h) << 16;
    float f; __builtin_memcpy(&f, &u, 4); return f;
}
__device__ __forceinline__ ushort_t f2bf(float f) {
    unsigned int u; __builtin_memcpy(&u, &f, 4);
    u = u + 0x7FFFu + ((u >> 16) & 1u);
    return (ushort_t)(u >> 16);
}

__global__ __launch_bounds__(256) void sentinel_kernel(float* out, int n, float val) {
    const int i = blockIdx.x * 256 + threadIdx.x;
    if (i < n) out[i] = val;
}

// Fused prep: [0,4096) x->x16 ; [4096,5120) E*C1->E16 ;
// [5120,5888) Wa transpose ; [5888,6144) Wp transpose.
__global__ __launch_bounds__(256) void prep_fused(
    const float* __restrict__ x, ushort_t* __restrict__ x16,
    const float* __restrict__ E, ushort_t* __restrict__ E16,
    const float* __restrict__ Wa, ushort_t* __restrict__ WaT,
    const float* __restrict__ Wp, ushort_t* __restrict__ WpT)
{
    __shared__ ushort_t t[64][65];
    const int bid = blockIdx.x;
    if (bid < 5120) {
        const float* src; ushort_t* dst; int base; float sc;
        if (bid < 4096) { src = x; dst = x16; base = bid * 1024; sc = 1.0f; }
        else            { src = E; dst = E16; base = (bid - 4096) * 1024; sc = C1; }
        const int i = base + (int)threadIdx.x * 4;
        const float4 v = *reinterpret_cast<const float4*>(src + i);
        union { unsigned long long u; ushort_t s[4]; } o;
        o.s[0] = f2bf(v.x * sc); o.s[1] = f2bf(v.y * sc);
        o.s[2] = f2bf(v.z * sc); o.s[3] = f2bf(v.w * sc);
        *reinterpret_cast<unsigned long long*>(dst + i) = o.u;
        return;
    }
    const float* W; ushort_t* Wt; int Kdim, Ndim, n0, k0;
    if (bid < 5888) {
        W = Wa; Wt = WaT; Kdim = 1024; Ndim = 3072;
        const int b = bid - 5120; n0 = (b % 48) * 64; k0 = (b / 48) * 64;
    } else {
        W = Wp; Wt = WpT; Kdim = 1024; Ndim = 1024;
        const int b = bid - 5888; n0 = (b % 16) * 64; k0 = (b / 16) * 64;
    }
    const int cx = threadIdx.x & 63, ry = threadIdx.x >> 6;
#pragma unroll
    for (int i = 0; i < 16; i++) {
        const int r = ry + i * 4;
        t[r][cx] = f2bf(W[(size_t)(k0 + r) * Ndim + n0 + cx]);
    }
    __syncthreads();
#pragma unroll
    for (int i = 0; i < 16; i++) {
        const int r = ry + i * 4;
        Wt[(size_t)(n0 + r) * Kdim + k0 + cx] = t[cx][r];
    }
}

// v[bh][t][d] bf16 -> vT[bh][d][t] bf16
__global__ __launch_bounds__(256) void transpose_v(
    const ushort_t* __restrict__ v, ushort_t* __restrict__ vT)
{
    __shared__ ushort_t t[64][65];
    const int bh = blockIdx.y;
    const int t0 = blockIdx.x * 64;
    const int cx = threadIdx.x & 63, ry = threadIdx.x >> 6;
    const ushort_t* src = v + (size_t)bh * 65536;
    ushort_t* dst = vT + (size_t)bh * 65536;
#pragma unroll
    for (int i = 0; i < 16; i++) {
        const int r = ry + i * 4;
        t[r][cx] = src[(size_t)(t0 + r) * HDIM + cx];
    }
    __syncthreads();
#pragma unroll
    for (int i = 0; i < 16; i++) {
        const int d = ry + i * 4;
        dst[(size_t)d * T_SEQ + t0 + cx] = t[cx][d];
    }
}

// ---------------------------------------------------------------------------
// m97-style MFMA GEMM (unchanged; q pre-scaled by C1 in MODE 0 epilogue).
// ---------------------------------------------------------------------------
template <int MODE>
__global__ __launch_bounds__(256) void gemm128(
    const ushort_t* __restrict__ A16, const ushort_t* __restrict__ Bt,
    const float* __restrict__ bias, void* __restrict__ out_,
    int Ndim, int Kdim)
{
    __shared__ __align__(16) ushort_t As[128 * 32];
    __shared__ __align__(16) ushort_t Bs[128 * 32];

    const int tid = threadIdx.x;
    const int w = tid >> 6;
    const int lane = tid & 63;
    const int l15 = lane & 15;
    const int quad = lane >> 4;
    const int m0 = blockIdx.y * 128, n0 = blockIdx.x * 128;
    const int wm = (w & 1) * 64, wn = (w >> 1) * 64;

    f32x4 acc[4][4];
#pragma unroll
    for (int mt = 0; mt < 4; mt++)
#pragma unroll
        for (int nt = 0; nt < 4; nt++) acc[mt][nt] = (f32x4){0.f, 0.f, 0.f, 0.f};

    for (int kk = 0; kk < Kdim; kk += 32) {
        __syncthreads();
#pragma unroll
        for (int t = 0; t < 2; t++) {
            const int chunk = w * 128 + t * 64 + lane;
            const int row = chunk >> 2, kc = (chunk & 3) * 8;
            __builtin_amdgcn_global_load_lds(
                (const __attribute__((address_space(1))) void*)
                    (A16 + (size_t)(m0 + row) * Kdim + kk + kc),
                (__attribute__((address_space(3))) void*)
                    (As + (size_t)(w * 128 + t * 64) * 8), 16, 0, 0);
            __builtin_amdgcn_global_load_lds(
                (const __attribute__((address_space(1))) void*)
                    (Bt + (size_t)(n0 + row) * Kdim + kk + kc),
                (__attribute__((address_space(3))) void*)
                    (Bs + (size_t)(w * 128 + t * 64) * 8), 16, 0, 0);
        }
        __syncthreads();

        bf16x8 af[4], bf[4];
#pragma unroll
        for (int mt = 0; mt < 4; mt++)
            af[mt] = *reinterpret_cast<const bf16x8*>(&As[(wm + mt * 16 + l15) * 32 + quad * 8]);
#pragma unroll
        for (int nt = 0; nt < 4; nt++)
            bf[nt] = *reinterpret_cast<const bf16x8*>(&Bs[(wn + nt * 16 + l15) * 32 + quad * 8]);
#pragma unroll
        for (int mt = 0; mt < 4; mt++)
#pragma unroll
            for (int nt = 0; nt < 4; nt++)
                acc[mt][nt] = __builtin_amdgcn_mfma_f32_16x16x32_bf16(
                    af[mt], bf[nt], acc[mt][nt], 0, 0, 0);
    }

#pragma unroll
    for (int mt = 0; mt < 4; mt++)
#pragma unroll
        for (int nt = 0; nt < 4; nt++) {
            const int n = n0 + wn + nt * 16 + l15;
            const float bv = bias[n];
#pragma unroll
            for (int r = 0; r < 4; r++) {
                const int m = m0 + wm + mt * 16 + quad * 4 + r;
                float val = acc[mt][nt][r] + bv;
                if (MODE == 0) {
                    ushort_t* ws = (ushort_t*)out_;
                    const int which = n >> 10;
                    if (which == 0) val *= C1;
                    const size_t pl = (which == 2) ? 3 : which;
                    const int cc = n & 1023;
                    const int h = cc >> 6, d = cc & 63;
                    const int b = m >> 10, t = m & 1023;
                    ws[pl * PLANE + ((size_t)(b * NHEAD + h) * T_SEQ + t) * HDIM + d] = f2bf(val);
                } else {
                    ((float*)out_)[(size_t)m * Ndim + n] = val;
                }
            }
        }
}

// ---------------------------------------------------------------------------
// Flash attention. Grid (16,64): block bx -> i-tile it=15-bx (LPT).
// Per tile: issue K/V/E global loads into short-lived regs BEFORE S1 (they
// fly during the barrier wait), commit via ds_write_b128 after S1 into
// XOR-chunk-swizzled rows (slot idx holds chunk (idx&7)^(row&7) of row
// idx>>3 -> conflict-free b128 frag reads). Ps: bf16 skew [il][jl] stride 68
// (2-way free). Probs alias Es rows [0,64) with same swizzle (post-S3).
// q & E pre-scaled by C1. LDS ~41.7 KB -> 3 blocks/CU.
// ---------------------------------------------------------------------------
__global__ __launch_bounds__(256) void flash_attn(
    const ushort_t* __restrict__ qp, const ushort_t* __restrict__ kp,
    const ushort_t* __restrict__ vTp, const ushort_t* __restrict__ E16,
    ushort_t* __restrict__ y16)
{
    __shared__ __align__(16) ushort_t Ks[64 * 64];
    __shared__ __align__(16) ushort_t Vt[64 * 64];
    __shared__ __align__(16) ushort_t Es[128 * 64];   // rows [0,64) alias probs
    __shared__ __align__(16) ushort_t Ps[65 * 68];    // row 64 = dump

    const int it = 15 - (int)blockIdx.x;
    const int bh = blockIdx.y;
    const int h = bh & (NHEAD - 1);
    const int b = bh >> 4;
    const int i0 = it * 64;
    const int tid = threadIdx.x;
    const int w = tid >> 6;
    const int lane = tid & 63;
    const int l15 = lane & 15;
    const int quad = lane >> 4;

    const size_t base = (size_t)bh * T_SEQ * HDIM;
    const ushort_t* Eh = E16 + (size_t)h * T_SEQ * HDIM;
    const ushort_t* vTb = vTp + (size_t)bh * 65536;

    // Q A-fragments from global (q pre-scaled by C1)
    bf16x8 qf[2];
    {
        const ushort_t* qrow = qp + base + (size_t)(i0 + w * 16 + l15) * HDIM;
        qf[0] = *reinterpret_cast<const bf16x8*>(qrow + quad * 8);
        qf[1] = *reinterpret_cast<const bf16x8*>(qrow + 32 + quad * 8);
    }

    f32x4 o[4], o5;
#pragma unroll
    for (int dt = 0; dt < 4; dt++) o[dt] = (f32x4){0.f, 0.f, 0.f, 0.f};
    o5 = (f32x4){0.f, 0.f, 0.f, 0.f};
    float mrow[4];
#pragma unroll
    for (int r = 0; r < 4; r++) mrow[r] = -3e38f;

    bf16x8 ones;
#pragma unroll
    for (int i = 0; i < 8; i++) ones[i] = (__bf16)1.0f;

    const int xsw = l15 & 7;

    for (int j0 = 0; j0 <= i0; j0 += 64) {
        const int d0 = i0 - j0;

        // ---- issue staging loads (short-lived regs; overlap barrier wait) ----
        uint4 kv[2], vv[2], ev[4];
#pragma unroll
        for (int t = 0; t < 2; t++) {
            const int idx = tid + t * 256;
            const int row = idx >> 3;
            const int g = (idx & 7) ^ (row & 7);
            kv[t] = *reinterpret_cast<const uint4*>(kp + base + (size_t)(j0 + row) * HDIM + g * 8);
            vv[t] = *reinterpret_cast<const uint4*>(vTb + (size_t)row * T_SEQ + j0 + g * 8);
        }
#pragma unroll
        for (int t = 0; t < 4; t++) {
            const int idx = tid + t * 256;
            const int row = idx >> 3;
            const int g = (idx & 7) ^ (row & 7);
            int gr = d0 - 64 + row;
            if (gr < 0) gr = 0;
            ev[t] = *reinterpret_cast<const uint4*>(Eh + (size_t)gr * HDIM + g * 8);
        }

        __syncthreads();   // S1: prev tile's LDS readers done
        // ---- commit to LDS (consecutive 16B per lane = conflict-free) ----
#pragma unroll
        for (int t = 0; t < 2; t++) {
            const int idx = tid + t * 256;
            *reinterpret_cast<uint4*>(&Ks[(size_t)idx * 8]) = kv[t];
            *reinterpret_cast<uint4*>(&Vt[(size_t)idx * 8]) = vv[t];
        }
#pragma unroll
        for (int t = 0; t < 4; t++) {
            const int idx = tid + t * 256;
            *reinterpret_cast<uint4*>(&Es[(size_t)idx * 8]) = ev[t];
        }
        __syncthreads();   // S2

        // ---- phase 1: S = Q@K^T ; P band = E@K^T ----
        f32x4 s[4], pb[2][4];
#pragma unroll
        for (int nt = 0; nt < 4; nt++) {
            s[nt] = (f32x4){0.f, 0.f, 0.f, 0.f};
            pb[0][nt] = (f32x4){0.f, 0.f, 0.f, 0.f};
            pb[1][nt] = (f32x4){0.f, 0.f, 0.f, 0.f};
        }
#pragma unroll
        for (int ks = 0; ks < 2; ks++) {
            const int cidx = (ks * 4 + quad) ^ xsw;
            const bf16x8 ae0 = *reinterpret_cast<const bf16x8*>(&Es[((w * 32 + l15) * 8 + cidx) * 8]);
            const bf16x8 ae1 = *reinterpret_cast<const bf16x8*>(&Es[((w * 32 + 16 + l15) * 8 + cidx) * 8]);
#pragma unroll
            for (int nt = 0; nt < 4; nt++) {
                const bf16x8 bk = *reinterpret_cast<const bf16x8*>(&Ks[((nt * 16 + l15) * 8 + cidx) * 8]);
                s[nt] = __builtin_amdgcn_mfma_f32_16x16x32_bf16(qf[ks], bk, s[nt], 0, 0, 0);
                pb[0][nt] = __builtin_amdgcn_mfma_f32_16x16x32_bf16(ae0, bk, pb[0][nt], 0, 0, 0);
                pb[1][nt] = __builtin_amdgcn_mfma_f32_16x16x32_bf16(ae1, bk, pb[1][nt], 0, 0, 0);
            }
        }
        // skew store: Ps[il_t][jl] stride 68; OOB -> dump row 64
#pragma unroll
        for (int mf = 0; mf < 2; mf++)
#pragma unroll
            for (int nt = 0; nt < 4; nt++) {
                const int jl = nt * 16 + l15;
#pragma unroll
                for (int r = 0; r < 4; r++) {
                    const int br = w * 32 + mf * 16 + quad * 4 + r;
                    const int il_t = br - 64 + jl;
                    const int addr = ((unsigned)il_t < 64u) ? il_t * 68 + jl : 64 * 68 + jl;
                    Ps[addr] = f2bf(pb[mf][nt][r]);
                }
            }
        __syncthreads();   // S3

        // ---- gather + online softmax (log2 domain) ----
        float pv[4][4], mnew[4];
#pragma unroll
        for (int r = 0; r < 4; r++) mnew[r] = mrow[r];
        const int il0 = w * 16 + quad * 4;
        if (j0 < i0) {
#pragma unroll
            for (int nt = 0; nt < 4; nt++) {
                const int jl = nt * 16 + l15;
#pragma unroll
                for (int r = 0; r < 4; r++) {
                    const float sv = s[nt][r] + bf2f(Ps[(il0 + r) * 68 + jl]);
                    pv[nt][r] = sv;
                    mnew[r] = fmaxf(mnew[r], sv);
                }
            }
        } else {
#pragma unroll
            for (int nt = 0; nt < 4; nt++) {
                const int jl = nt * 16 + l15;
#pragma unroll
                for (int r = 0; r < 4; r++) {
                    const int il = il0 + r;
                    float sv = s[nt][r] + bf2f(Ps[il * 68 + jl]);
                    if (jl > il) sv = -3e38f;
                    pv[nt][r] = sv;
                    mnew[r] = fmaxf(mnew[r], sv);
                }
            }
        }
#pragma unroll
        for (int r = 0; r < 4; r++)
#pragma unroll
            for (int off = 1; off < 16; off <<= 1)
                mnew[r] = fmaxf(mnew[r], __shfl_xor(mnew[r], off, 64));
        float alpha[4];
#pragma unroll
        for (int r = 0; r < 4; r++) {
            alpha[r] = exp2f(mrow[r] - mnew[r]);
            mrow[r] = mnew[r];
        }
#pragma unroll
        for (int nt = 0; nt < 4; nt++)
#pragma unroll
            for (int r = 0; r < 4; r++)
                pv[nt][r] = exp2f(pv[nt][r] - mnew[r]);
#pragma unroll
        for (int dt = 0; dt < 4; dt++)
#pragma unroll
            for (int r = 0; r < 4; r++) o[dt][r] *= alpha[r];
#pragma unroll
        for (int r = 0; r < 4; r++) o5[r] *= alpha[r];
        // probs -> Es rows [0,64), swizzled chunks (free after phase-1 reads)
#pragma unroll
        for (int nt = 0; nt < 4; nt++) {
            const int jl = nt * 16 + l15;
#pragma unroll
            for (int r = 0; r < 4; r++) {
                const int row = il0 + r;
                Es[(row * 8 + ((jl >> 3) ^ (row & 7))) * 8 + (jl & 7)] = f2bf(pv[nt][r]);
            }
        }
        __syncthreads();   // S4

        // ---- O += P @ V ; denominator via ones column ----
#pragma unroll
        for (int ks = 0; ks < 2; ks++) {
            const int cidx = (ks * 4 + quad) ^ xsw;
            const bf16x8 ap = *reinterpret_cast<const bf16x8*>(&Es[((w * 16 + l15) * 8 + cidx) * 8]);
#pragma unroll
            for (int dt = 0; dt < 4; dt++) {
                const bf16x8 bv = *reinterpret_cast<const bf16x8*>(&Vt[((dt * 16 + l15) * 8 + cidx) * 8]);
                o[dt] = __builtin_amdgcn_mfma_f32_16x16x32_bf16(ap, bv, o[dt], 0, 0, 0);
            }
            o5 = __builtin_amdgcn_mfma_f32_16x16x32_bf16(ap, ones, o5, 0, 0, 0);
        }
    }

    // ---- epilogue ----
    float inv[4];
#pragma unroll
    for (int r = 0; r < 4; r++) inv[r] = 1.0f / o5[r];
#pragma unroll
    for (int dt = 0; dt < 4; dt++)
#pragma unroll
        for (int r = 0; r < 4; r++) {
            const int il = w * 16 + quad * 4 + r;
            const int d = dt * 16 + l15;
            y16[((size_t)(b * T_SEQ + i0 + il)) * 1024 + h * 64 + d] = f2bf(o[dt][r] * inv[r]);
        }
}

extern "C" void kernel_launch(void* const* d_in, const int* in_sizes, int n_in,
                              void* d_out, int out_size, void* d_ws, size_t ws_size,
                              hipStream_t stream) {
    float* out = (float*)d_out;

    const void* x = nullptr; const void* Wa = nullptr; const void* ba = nullptr;
    const void* Wp = nullptr; const void* bp = nullptr; const void* E = nullptr;
    int anomaly = 0;
    if (n_in != 6) {
        anomaly = 2;
    } else {
        int c1M = 0;
        for (int i = 0; i < 6; i++) {
            const int s = in_sizes[i];
            if      (s == 4194304) x  = d_in[i];
            else if (s == 3145728) Wa = d_in[i];
            else if (s == 3072)    ba = d_in[i];
            else if (s == 1024)    bp = d_in[i];
            else if (s == 1048576) { if (c1M == 0) Wp = d_in[i]; else E = d_in[i]; c1M++; }
            else anomaly = 1;
        }
        if (!x || !Wa || !ba || !Wp || !bp || !E || c1M != 2) anomaly = 1;
    }
    if (!anomaly && out_size != 4194304) anomaly = 3;
    if (!anomaly && ws_size < (size_t)52428800) anomaly = 4;
    if (anomaly) {
        sentinel_kernel<<<(out_size + 255) / 256, 256, 0, stream>>>(out, out_size, 1000.0f * anomaly);
        return;
    }

    ushort_t* ws   = (ushort_t*)d_ws;
    ushort_t* qp   = ws;
    ushort_t* kp   = ws + (size_t)PLANE;
    ushort_t* vTp  = ws + (size_t)2 * PLANE;
    ushort_t* vtmp = ws + (size_t)3 * PLANE;
    ushort_t* y16  = vtmp;
    ushort_t* x16  = ws + (size_t)4 * PLANE;
    ushort_t* WaT  = ws + (size_t)5 * PLANE;
    ushort_t* WpT  = WaT + (size_t)3145728;
    ushort_t* E16  = WpT + (size_t)1048576;

    prep_fused<<<6144, 256, 0, stream>>>(
        (const float*)x, x16, (const float*)E, E16,
        (const float*)Wa, WaT, (const float*)Wp, WpT);

    gemm128<0><<<dim3(24, 32), 256, 0, stream>>>(x16, WaT, (const float*)ba, (void*)ws, 3072, 1024);

    transpose_v<<<dim3(16, 64), 256, 0, stream>>>(vtmp, vTp);

    flash_attn<<<dim3(16, 64), 256, 0, stream>>>(qp, kp, vTp, E16, y16);

    gemm128<1><<<dim3(8, 32), 256, 0, stream>>>(y16, WpT, (const float*)bp, (void*)out, 1024, 1024);
}

// Round 13
// 262.027 us; speedup vs baseline: 1.4706x; 1.4706x over previous
//
#include <hip/hip_runtime.h>

// SelfAttention (B=4, T=1024, C=1024, H=16, HD=64). fp32 in / fp32 out.
// R13 = R9 control flow (stage AFTER S1, load->reg->ds_write immediately:
// zero cross-barrier register liveness -- the compiler spills any VGPR held
// across __syncthreads, proven R11 244MB / R12 100MB scratch)
// + R10 conflict-free addressing (XOR-chunk swizzle K/V/E/probs, Ps stride-68
// skew), which R10 proved spill-free (WRITE 8MB).
// ws (50 MiB): q(0) k(1) vT(2) vtmp/y16(3) x16(4) WaT WpT E16.

typedef __bf16 bf16x8 __attribute__((ext_vector_type(8)));
typedef float f32x4 __attribute__((ext_vector_type(4)));
typedef unsigned short ushort_t;

#define T_SEQ 1024
#define NHEAD 16
#define HDIM 64
#define PLANE 4194304
#define C1 0.1803368801f   // 0.125 * log2(e)

__device__ __forceinline__ float bf2f(ushort_t h) {
    unsigned int u = ((unsigned int)h) << 16;
    float f; __builtin_memcpy(&f, &u, 4); return f;
}
__device__ __forceinline__ ushort_t f2bf(float f) {
    unsigned int u; __builtin_memcpy(&u, &f, 4);
    u = u + 0x7FFFu + ((u >> 16) & 1u);
    return (ushort_t)(u >> 16);
}

__global__ __launch_bounds__(256) void sentinel_kernel(float* out, int n, float val) {
    const int i = blockIdx.x * 256 + threadIdx.x;
    if (i < n) out[i] = val;
}

// Fused prep: [0,4096) x->x16 ; [4096,5120) E*C1->E16 ;
// [5120,5888) Wa transpose ; [5888,6144) Wp transpose.
__global__ __launch_bounds__(256) void prep_fused(
    const float* __restrict__ x, ushort_t* __restrict__ x16,
    const float* __restrict__ E, ushort_t* __restrict__ E16,
    const float* __restrict__ Wa, ushort_t* __restrict__ WaT,
    const float* __restrict__ Wp, ushort_t* __restrict__ WpT)
{
    __shared__ ushort_t t[64][65];
    const int bid = blockIdx.x;
    if (bid < 5120) {
        const float* src; ushort_t* dst; int base; float sc;
        if (bid < 4096) { src = x; dst = x16; base = bid * 1024; sc = 1.0f; }
        else            { src = E; dst = E16; base = (bid - 4096) * 1024; sc = C1; }
        const int i = base + (int)threadIdx.x * 4;
        const float4 v = *reinterpret_cast<const float4*>(src + i);
        union { unsigned long long u; ushort_t s[4]; } o;
        o.s[0] = f2bf(v.x * sc); o.s[1] = f2bf(v.y * sc);
        o.s[2] = f2bf(v.z * sc); o.s[3] = f2bf(v.w * sc);
        *reinterpret_cast<unsigned long long*>(dst + i) = o.u;
        return;
    }
    const float* W; ushort_t* Wt; int Kdim, Ndim, n0, k0;
    if (bid < 5888) {
        W = Wa; Wt = WaT; Kdim = 1024; Ndim = 3072;
        const int b = bid - 5120; n0 = (b % 48) * 64; k0 = (b / 48) * 64;
    } else {
        W = Wp; Wt = WpT; Kdim = 1024; Ndim = 1024;
        const int b = bid - 5888; n0 = (b % 16) * 64; k0 = (b / 16) * 64;
    }
    const int cx = threadIdx.x & 63, ry = threadIdx.x >> 6;
#pragma unroll
    for (int i = 0; i < 16; i++) {
        const int r = ry + i * 4;
        t[r][cx] = f2bf(W[(size_t)(k0 + r) * Ndim + n0 + cx]);
    }
    __syncthreads();
#pragma unroll
    for (int i = 0; i < 16; i++) {
        const int r = ry + i * 4;
        Wt[(size_t)(n0 + r) * Kdim + k0 + cx] = t[cx][r];
    }
}

// v[bh][t][d] bf16 -> vT[bh][d][t] bf16
__global__ __launch_bounds__(256) void transpose_v(
    const ushort_t* __restrict__ v, ushort_t* __restrict__ vT)
{
    __shared__ ushort_t t[64][65];
    const int bh = blockIdx.y;
    const int t0 = blockIdx.x * 64;
    const int cx = threadIdx.x & 63, ry = threadIdx.x >> 6;
    const ushort_t* src = v + (size_t)bh * 65536;
    ushort_t* dst = vT + (size_t)bh * 65536;
#pragma unroll
    for (int i = 0; i < 16; i++) {
        const int r = ry + i * 4;
        t[r][cx] = src[(size_t)(t0 + r) * HDIM + cx];
    }
    __syncthreads();
#pragma unroll
    for (int i = 0; i < 16; i++) {
        const int d = ry + i * 4;
        dst[(size_t)d * T_SEQ + t0 + cx] = t[cx][d];
    }
}

// ---------------------------------------------------------------------------
// m97-style MFMA GEMM (q pre-scaled by C1 in MODE 0 epilogue).
// ---------------------------------------------------------------------------
template <int MODE>
__global__ __launch_bounds__(256) void gemm128(
    const ushort_t* __restrict__ A16, const ushort_t* __restrict__ Bt,
    const float* __restrict__ bias, void* __restrict__ out_,
    int Ndim, int Kdim)
{
    __shared__ __align__(16) ushort_t As[128 * 32];
    __shared__ __align__(16) ushort_t Bs[128 * 32];

    const int tid = threadIdx.x;
    const int w = tid >> 6;
    const int lane = tid & 63;
    const int l15 = lane & 15;
    const int quad = lane >> 4;
    const int m0 = blockIdx.y * 128, n0 = blockIdx.x * 128;
    const int wm = (w & 1) * 64, wn = (w >> 1) * 64;

    f32x4 acc[4][4];
#pragma unroll
    for (int mt = 0; mt < 4; mt++)
#pragma unroll
        for (int nt = 0; nt < 4; nt++) acc[mt][nt] = (f32x4){0.f, 0.f, 0.f, 0.f};

    for (int kk = 0; kk < Kdim; kk += 32) {
        __syncthreads();
#pragma unroll
        for (int t = 0; t < 2; t++) {
            const int chunk = w * 128 + t * 64 + lane;
            const int row = chunk >> 2, kc = (chunk & 3) * 8;
            __builtin_amdgcn_global_load_lds(
                (const __attribute__((address_space(1))) void*)
                    (A16 + (size_t)(m0 + row) * Kdim + kk + kc),
                (__attribute__((address_space(3))) void*)
                    (As + (size_t)(w * 128 + t * 64) * 8), 16, 0, 0);
            __builtin_amdgcn_global_load_lds(
                (const __attribute__((address_space(1))) void*)
                    (Bt + (size_t)(n0 + row) * Kdim + kk + kc),
                (__attribute__((address_space(3))) void*)
                    (Bs + (size_t)(w * 128 + t * 64) * 8), 16, 0, 0);
        }
        __syncthreads();

        bf16x8 af[4], bf[4];
#pragma unroll
        for (int mt = 0; mt < 4; mt++)
            af[mt] = *reinterpret_cast<const bf16x8*>(&As[(wm + mt * 16 + l15) * 32 + quad * 8]);
#pragma unroll
        for (int nt = 0; nt < 4; nt++)
            bf[nt] = *reinterpret_cast<const bf16x8*>(&Bs[(wn + nt * 16 + l15) * 32 + quad * 8]);
#pragma unroll
        for (int mt = 0; mt < 4; mt++)
#pragma unroll
            for (int nt = 0; nt < 4; nt++)
                acc[mt][nt] = __builtin_amdgcn_mfma_f32_16x16x32_bf16(
                    af[mt], bf[nt], acc[mt][nt], 0, 0, 0);
    }

#pragma unroll
    for (int mt = 0; mt < 4; mt++)
#pragma unroll
        for (int nt = 0; nt < 4; nt++) {
            const int n = n0 + wn + nt * 16 + l15;
            const float bv = bias[n];
#pragma unroll
            for (int r = 0; r < 4; r++) {
                const int m = m0 + wm + mt * 16 + quad * 4 + r;
                float val = acc[mt][nt][r] + bv;
                if (MODE == 0) {
                    ushort_t* ws = (ushort_t*)out_;
                    const int which = n >> 10;
                    if (which == 0) val *= C1;
                    const size_t pl = (which == 2) ? 3 : which;
                    const int cc = n & 1023;
                    const int h = cc >> 6, d = cc & 63;
                    const int b = m >> 10, t = m & 1023;
                    ws[pl * PLANE + ((size_t)(b * NHEAD + h) * T_SEQ + t) * HDIM + d] = f2bf(val);
                } else {
                    ((float*)out_)[(size_t)m * Ndim + n] = val;
                }
            }
        }
}

// ---------------------------------------------------------------------------
// Flash attention. Grid (16,64): block bx -> i-tile it=15-bx (LPT).
// Staging AFTER S1: global load -> reg -> immediate ds_write_b128 (values
// never live across a barrier => no spill). XOR-chunk-swizzled rows: slot
// idx holds chunk (idx&7)^(row&7) of row idx>>3 -> conflict-free b128 frag
// reads. Ps: bf16 skew [il][jl] stride 68 (2-way free). Probs alias Es rows
// [0,64) same swizzle. q & E pre-scaled by C1. LDS ~41.7 KB -> 3 blocks/CU.
// ---------------------------------------------------------------------------
__global__ __launch_bounds__(256) void flash_attn(
    const ushort_t* __restrict__ qp, const ushort_t* __restrict__ kp,
    const ushort_t* __restrict__ vTp, const ushort_t* __restrict__ E16,
    ushort_t* __restrict__ y16)
{
    __shared__ __align__(16) ushort_t Ks[64 * 64];
    __shared__ __align__(16) ushort_t Vt[64 * 64];
    __shared__ __align__(16) ushort_t Es[128 * 64];   // rows [0,64) alias probs
    __shared__ __align__(16) ushort_t Ps[65 * 68];    // row 64 = dump

    const int it = 15 - (int)blockIdx.x;
    const int bh = blockIdx.y;
    const int h = bh & (NHEAD - 1);
    const int b = bh >> 4;
    const int i0 = it * 64;
    const int tid = threadIdx.x;
    const int w = tid >> 6;
    const int lane = tid & 63;
    const int l15 = lane & 15;
    const int quad = lane >> 4;

    const size_t base = (size_t)bh * T_SEQ * HDIM;
    const ushort_t* Eh = E16 + (size_t)h * T_SEQ * HDIM;
    const ushort_t* vTb = vTp + (size_t)bh * 65536;

    // Q A-fragments from global (q pre-scaled by C1)
    bf16x8 qf[2];
    {
        const ushort_t* qrow = qp + base + (size_t)(i0 + w * 16 + l15) * HDIM;
        qf[0] = *reinterpret_cast<const bf16x8*>(qrow + quad * 8);
        qf[1] = *reinterpret_cast<const bf16x8*>(qrow + 32 + quad * 8);
    }

    f32x4 o[4], o5;
#pragma unroll
    for (int dt = 0; dt < 4; dt++) o[dt] = (f32x4){0.f, 0.f, 0.f, 0.f};
    o5 = (f32x4){0.f, 0.f, 0.f, 0.f};
    float mrow[4];
#pragma unroll
    for (int r = 0; r < 4; r++) mrow[r] = -3e38f;

    bf16x8 ones;
#pragma unroll
    for (int i = 0; i < 8; i++) ones[i] = (__bf16)1.0f;

    const int xsw = l15 & 7;

    for (int j0 = 0; j0 <= i0; j0 += 64) {
        const int d0 = i0 - j0;

        __syncthreads();   // S1: prev tile's LDS readers done
        // ---- stage K/V/E: load -> immediate ds_write (no barrier crossing) ----
#pragma unroll
        for (int t = 0; t < 2; t++) {
            const int idx = tid + t * 256;
            const int row = idx >> 3;
            const int g = (idx & 7) ^ (row & 7);
            const uint4 kv = *reinterpret_cast<const uint4*>(
                kp + base + (size_t)(j0 + row) * HDIM + g * 8);
            *reinterpret_cast<uint4*>(&Ks[(size_t)idx * 8]) = kv;
            const uint4 vv = *reinterpret_cast<const uint4*>(
                vTb + (size_t)row * T_SEQ + j0 + g * 8);
            *reinterpret_cast<uint4*>(&Vt[(size_t)idx * 8]) = vv;
        }
#pragma unroll
        for (int t = 0; t < 4; t++) {
            const int idx = tid + t * 256;
            const int row = idx >> 3;
            const int g = (idx & 7) ^ (row & 7);
            int gr = d0 - 64 + row;
            if (gr < 0) gr = 0;
            const uint4 ev = *reinterpret_cast<const uint4*>(
                Eh + (size_t)gr * HDIM + g * 8);
            *reinterpret_cast<uint4*>(&Es[(size_t)idx * 8]) = ev;
        }
        __syncthreads();   // S2

        // ---- phase 1: S = Q@K^T ; P band = E@K^T ----
        f32x4 s[4], pb[2][4];
#pragma unroll
        for (int nt = 0; nt < 4; nt++) {
            s[nt] = (f32x4){0.f, 0.f, 0.f, 0.f};
            pb[0][nt] = (f32x4){0.f, 0.f, 0.f, 0.f};
            pb[1][nt] = (f32x4){0.f, 0.f, 0.f, 0.f};
        }
#pragma unroll
        for (int ks = 0; ks < 2; ks++) {
            const int cidx = (ks * 4 + quad) ^ xsw;
            const bf16x8 ae0 = *reinterpret_cast<const bf16x8*>(&Es[((w * 32 + l15) * 8 + cidx) * 8]);
            const bf16x8 ae1 = *reinterpret_cast<const bf16x8*>(&Es[((w * 32 + 16 + l15) * 8 + cidx) * 8]);
#pragma unroll
            for (int nt = 0; nt < 4; nt++) {
                const bf16x8 bk = *reinterpret_cast<const bf16x8*>(&Ks[((nt * 16 + l15) * 8 + cidx) * 8]);
                s[nt] = __builtin_amdgcn_mfma_f32_16x16x32_bf16(qf[ks], bk, s[nt], 0, 0, 0);
                pb[0][nt] = __builtin_amdgcn_mfma_f32_16x16x32_bf16(ae0, bk, pb[0][nt], 0, 0, 0);
                pb[1][nt] = __builtin_amdgcn_mfma_f32_16x16x32_bf16(ae1, bk, pb[1][nt], 0, 0, 0);
            }
        }
        // skew store: Ps[il_t][jl] stride 68; OOB -> dump row 64
#pragma unroll
        for (int mf = 0; mf < 2; mf++)
#pragma unroll
            for (int nt = 0; nt < 4; nt++) {
                const int jl = nt * 16 + l15;
#pragma unroll
                for (int r = 0; r < 4; r++) {
                    const int br = w * 32 + mf * 16 + quad * 4 + r;
                    const int il_t = br - 64 + jl;
                    const int addr = ((unsigned)il_t < 64u) ? il_t * 68 + jl : 64 * 68 + jl;
                    Ps[addr] = f2bf(pb[mf][nt][r]);
                }
            }
        __syncthreads();   // S3

        // ---- gather + online softmax (log2 domain) ----
        float pv[4][4], mnew[4];
#pragma unroll
        for (int r = 0; r < 4; r++) mnew[r] = mrow[r];
        const int il0 = w * 16 + quad * 4;
        if (j0 < i0) {
#pragma unroll
            for (int nt = 0; nt < 4; nt++) {
                const int jl = nt * 16 + l15;
#pragma unroll
                for (int r = 0; r < 4; r++) {
                    const float sv = s[nt][r] + bf2f(Ps[(il0 + r) * 68 + jl]);
                    pv[nt][r] = sv;
                    mnew[r] = fmaxf(mnew[r], sv);
                }
            }
        } else {
#pragma unroll
            for (int nt = 0; nt < 4; nt++) {
                const int jl = nt * 16 + l15;
#pragma unroll
                for (int r = 0; r < 4; r++) {
                    const int il = il0 + r;
                    float sv = s[nt][r] + bf2f(Ps[il * 68 + jl]);
                    if (jl > il) sv = -3e38f;
                    pv[nt][r] = sv;
                    mnew[r] = fmaxf(mnew[r], sv);
                }
            }
        }
#pragma unroll
        for (int r = 0; r < 4; r++)
#pragma unroll
            for (int off = 1; off < 16; off <<= 1)
                mnew[r] = fmaxf(mnew[r], __shfl_xor(mnew[r], off, 64));
        float alpha[4];
#pragma unroll
        for (int r = 0; r < 4; r++) {
            alpha[r] = exp2f(mrow[r] - mnew[r]);
            mrow[r] = mnew[r];
        }
#pragma unroll
        for (int nt = 0; nt < 4; nt++)
#pragma unroll
            for (int r = 0; r < 4; r++)
                pv[nt][r] = exp2f(pv[nt][r] - mnew[r]);
#pragma unroll
        for (int dt = 0; dt < 4; dt++)
#pragma unroll
            for (int r = 0; r < 4; r++) o[dt][r] *= alpha[r];
#pragma unroll
        for (int r = 0; r < 4; r++) o5[r] *= alpha[r];
        // probs -> Es rows [0,64), swizzled chunks (free after phase-1 reads)
#pragma unroll
        for (int nt = 0; nt < 4; nt++) {
            const int jl = nt * 16 + l15;
#pragma unroll
            for (int r = 0; r < 4; r++) {
                const int row = il0 + r;
                Es[(row * 8 + ((jl >> 3) ^ (row & 7))) * 8 + (jl & 7)] = f2bf(pv[nt][r]);
            }
        }
        __syncthreads();   // S4

        // ---- O += P @ V ; denominator via ones column ----
#pragma unroll
        for (int ks = 0; ks < 2; ks++) {
            const int cidx = (ks * 4 + quad) ^ xsw;
            const bf16x8 ap = *reinterpret_cast<const bf16x8*>(&Es[((w * 16 + l15) * 8 + cidx) * 8]);
#pragma unroll
            for (int dt = 0; dt < 4; dt++) {
                const bf16x8 bv = *reinterpret_cast<const bf16x8*>(&Vt[((dt * 16 + l15) * 8 + cidx) * 8]);
                o[dt] = __builtin_amdgcn_mfma_f32_16x16x32_bf16(ap, bv, o[dt], 0, 0, 0);
            }
            o5 = __builtin_amdgcn_mfma_f32_16x16x32_bf16(ap, ones, o5, 0, 0, 0);
        }
    }

    // ---- epilogue ----
    float inv[4];
#pragma unroll
    for (int r = 0; r < 4; r++) inv[r] = 1.0f / o5[r];
#pragma unroll
    for (int dt = 0; dt < 4; dt++)
#pragma unroll
        for (int r = 0; r < 4; r++) {
            const int il = w * 16 + quad * 4 + r;
            const int d = dt * 16 + l15;
            y16[((size_t)(b * T_SEQ + i0 + il)) * 1024 + h * 64 + d] = f2bf(o[dt][r] * inv[r]);
        }
}

extern "C" void kernel_launch(void* const* d_in, const int* in_sizes, int n_in,
                              void* d_out, int out_size, void* d_ws, size_t ws_size,
                              hipStream_t stream) {
    float* out = (float*)d_out;

    const void* x = nullptr; const void* Wa = nullptr; const void* ba = nullptr;
    const void* Wp = nullptr; const void* bp = nullptr; const void* E = nullptr;
    int anomaly = 0;
    if (n_in != 6) {
        anomaly = 2;
    } else {
        int c1M = 0;
        for (int i = 0; i < 6; i++) {
            const int s = in_sizes[i];
            if      (s == 4194304) x  = d_in[i];
            else if (s == 3145728) Wa = d_in[i];
            else if (s == 3072)    ba = d_in[i];
            else if (s == 1024)    bp = d_in[i];
            else if (s == 1048576) { if (c1M == 0) Wp = d_in[i]; else E = d_in[i]; c1M++; }
            else anomaly = 1;
        }
        if (!x || !Wa || !ba || !Wp || !bp || !E || c1M != 2) anomaly = 1;
    }
    if (!anomaly && out_size != 4194304) anomaly = 3;
    if (!anomaly && ws_size < (size_t)52428800) anomaly = 4;
    if (anomaly) {
        sentinel_kernel<<<(out_size + 255) / 256, 256, 0, stream>>>(out, out_size, 1000.0f * anomaly);
        return;
    }

    ushort_t* ws   = (ushort_t*)d_ws;
    ushort_t* qp   = ws;
    ushort_t* kp   = ws + (size_t)PLANE;
    ushort_t* vTp  = ws + (size_t)2 * PLANE;
    ushort_t* vtmp = ws + (size_t)3 * PLANE;
    ushort_t* y16  = vtmp;
    ushort_t* x16  = ws + (size_t)4 * PLANE;
    ushort_t* WaT  = ws + (size_t)5 * PLANE;
    ushort_t* WpT  = WaT + (size_t)3145728;
    ushort_t* E16  = WpT + (size_t)1048576;

    prep_fused<<<6144, 256, 0, stream>>>(
        (const float*)x, x16, (const float*)E, E16,
        (const float*)Wa, WaT, (const float*)Wp, WpT);

    gemm128<0><<<dim3(24, 32), 256, 0, stream>>>(x16, WaT, (const float*)ba, (void*)ws, 3072, 1024);

    transpose_v<<<dim3(16, 64), 256, 0, stream>>>(vtmp, vTp);

    flash_attn<<<dim3(16, 64), 256, 0, stream>>>(qp, kp, vTp, E16, y16);

    gemm128<1><<<dim3(8, 32), 256, 0, stream>>>(y16, WpT, (const float*)bp, (void*)out, 1024, 1024);
}

// Round 14
// 249.692 us; speedup vs baseline: 1.5433x; 1.0494x over previous
//
#include <hip/hip_runtime.h>

// SelfAttention (B=4, T=1024, C=1024, H=16, HD=64). fp32 in / fp32 out.
// R14 = R13 flash body (stage AFTER S1 load->ds_write: no cross-barrier reg
// liveness => no spill [R11/R12 lesson]; XOR-chunk swizzle + Ps stride-68:
// conflicts 8.3M->1.4M [R10 lesson]) + R9's PAIRED UNIFORM GRID (8,64):
// block bx does i-tiles {15-bx, bx} = 17 j-tiles each -- kills the
// load-imbalance tail that halved occupancy in R10/R13.
// ws (50 MiB): q(0) k(1) vT(2) vtmp/y16(3) x16(4) WaT WpT E16.

typedef __bf16 bf16x8 __attribute__((ext_vector_type(8)));
typedef float f32x4 __attribute__((ext_vector_type(4)));
typedef unsigned short ushort_t;

#define T_SEQ 1024
#define NHEAD 16
#define HDIM 64
#define PLANE 4194304
#define C1 0.1803368801f   // 0.125 * log2(e)

__device__ __forceinline__ float bf2f(ushort_t h) {
    unsigned int u = ((unsigned int)h) << 16;
    float f; __builtin_memcpy(&f, &u, 4); return f;
}
__device__ __forceinline__ ushort_t f2bf(float f) {
    unsigned int u; __builtin_memcpy(&u, &f, 4);
    u = u + 0x7FFFu + ((u >> 16) & 1u);
    return (ushort_t)(u >> 16);
}

__global__ __launch_bounds__(256) void sentinel_kernel(float* out, int n, float val) {
    const int i = blockIdx.x * 256 + threadIdx.x;
    if (i < n) out[i] = val;
}

// Fused prep: [0,4096) x->x16 ; [4096,5120) E*C1->E16 ;
// [5120,5888) Wa transpose ; [5888,6144) Wp transpose.
__global__ __launch_bounds__(256) void prep_fused(
    const float* __restrict__ x, ushort_t* __restrict__ x16,
    const float* __restrict__ E, ushort_t* __restrict__ E16,
    const float* __restrict__ Wa, ushort_t* __restrict__ WaT,
    const float* __restrict__ Wp, ushort_t* __restrict__ WpT)
{
    __shared__ ushort_t t[64][65];
    const int bid = blockIdx.x;
    if (bid < 5120) {
        const float* src; ushort_t* dst; int base; float sc;
        if (bid < 4096) { src = x; dst = x16; base = bid * 1024; sc = 1.0f; }
        else            { src = E; dst = E16; base = (bid - 4096) * 1024; sc = C1; }
        const int i = base + (int)threadIdx.x * 4;
        const float4 v = *reinterpret_cast<const float4*>(src + i);
        union { unsigned long long u; ushort_t s[4]; } o;
        o.s[0] = f2bf(v.x * sc); o.s[1] = f2bf(v.y * sc);
        o.s[2] = f2bf(v.z * sc); o.s[3] = f2bf(v.w * sc);
        *reinterpret_cast<unsigned long long*>(dst + i) = o.u;
        return;
    }
    const float* W; ushort_t* Wt; int Kdim, Ndim, n0, k0;
    if (bid < 5888) {
        W = Wa; Wt = WaT; Kdim = 1024; Ndim = 3072;
        const int b = bid - 5120; n0 = (b % 48) * 64; k0 = (b / 48) * 64;
    } else {
        W = Wp; Wt = WpT; Kdim = 1024; Ndim = 1024;
        const int b = bid - 5888; n0 = (b % 16) * 64; k0 = (b / 16) * 64;
    }
    const int cx = threadIdx.x & 63, ry = threadIdx.x >> 6;
#pragma unroll
    for (int i = 0; i < 16; i++) {
        const int r = ry + i * 4;
        t[r][cx] = f2bf(W[(size_t)(k0 + r) * Ndim + n0 + cx]);
    }
    __syncthreads();
#pragma unroll
    for (int i = 0; i < 16; i++) {
        const int r = ry + i * 4;
        Wt[(size_t)(n0 + r) * Kdim + k0 + cx] = t[cx][r];
    }
}

// v[bh][t][d] bf16 -> vT[bh][d][t] bf16
__global__ __launch_bounds__(256) void transpose_v(
    const ushort_t* __restrict__ v, ushort_t* __restrict__ vT)
{
    __shared__ ushort_t t[64][65];
    const int bh = blockIdx.y;
    const int t0 = blockIdx.x * 64;
    const int cx = threadIdx.x & 63, ry = threadIdx.x >> 6;
    const ushort_t* src = v + (size_t)bh * 65536;
    ushort_t* dst = vT + (size_t)bh * 65536;
#pragma unroll
    for (int i = 0; i < 16; i++) {
        const int r = ry + i * 4;
        t[r][cx] = src[(size_t)(t0 + r) * HDIM + cx];
    }
    __syncthreads();
#pragma unroll
    for (int i = 0; i < 16; i++) {
        const int d = ry + i * 4;
        dst[(size_t)d * T_SEQ + t0 + cx] = t[cx][d];
    }
}

// ---------------------------------------------------------------------------
// m97-style MFMA GEMM (q pre-scaled by C1 in MODE 0 epilogue).
// ---------------------------------------------------------------------------
template <int MODE>
__global__ __launch_bounds__(256) void gemm128(
    const ushort_t* __restrict__ A16, const ushort_t* __restrict__ Bt,
    const float* __restrict__ bias, void* __restrict__ out_,
    int Ndim, int Kdim)
{
    __shared__ __align__(16) ushort_t As[128 * 32];
    __shared__ __align__(16) ushort_t Bs[128 * 32];

    const int tid = threadIdx.x;
    const int w = tid >> 6;
    const int lane = tid & 63;
    const int l15 = lane & 15;
    const int quad = lane >> 4;
    const int m0 = blockIdx.y * 128, n0 = blockIdx.x * 128;
    const int wm = (w & 1) * 64, wn = (w >> 1) * 64;

    f32x4 acc[4][4];
#pragma unroll
    for (int mt = 0; mt < 4; mt++)
#pragma unroll
        for (int nt = 0; nt < 4; nt++) acc[mt][nt] = (f32x4){0.f, 0.f, 0.f, 0.f};

    for (int kk = 0; kk < Kdim; kk += 32) {
        __syncthreads();
#pragma unroll
        for (int t = 0; t < 2; t++) {
            const int chunk = w * 128 + t * 64 + lane;
            const int row = chunk >> 2, kc = (chunk & 3) * 8;
            __builtin_amdgcn_global_load_lds(
                (const __attribute__((address_space(1))) void*)
                    (A16 + (size_t)(m0 + row) * Kdim + kk + kc),
                (__attribute__((address_space(3))) void*)
                    (As + (size_t)(w * 128 + t * 64) * 8), 16, 0, 0);
            __builtin_amdgcn_global_load_lds(
                (const __attribute__((address_space(1))) void*)
                    (Bt + (size_t)(n0 + row) * Kdim + kk + kc),
                (__attribute__((address_space(3))) void*)
                    (Bs + (size_t)(w * 128 + t * 64) * 8), 16, 0, 0);
        }
        __syncthreads();

        bf16x8 af[4], bf[4];
#pragma unroll
        for (int mt = 0; mt < 4; mt++)
            af[mt] = *reinterpret_cast<const bf16x8*>(&As[(wm + mt * 16 + l15) * 32 + quad * 8]);
#pragma unroll
        for (int nt = 0; nt < 4; nt++)
            bf[nt] = *reinterpret_cast<const bf16x8*>(&Bs[(wn + nt * 16 + l15) * 32 + quad * 8]);
#pragma unroll
        for (int mt = 0; mt < 4; mt++)
#pragma unroll
            for (int nt = 0; nt < 4; nt++)
                acc[mt][nt] = __builtin_amdgcn_mfma_f32_16x16x32_bf16(
                    af[mt], bf[nt], acc[mt][nt], 0, 0, 0);
    }

#pragma unroll
    for (int mt = 0; mt < 4; mt++)
#pragma unroll
        for (int nt = 0; nt < 4; nt++) {
            const int n = n0 + wn + nt * 16 + l15;
            const float bv = bias[n];
#pragma unroll
            for (int r = 0; r < 4; r++) {
                const int m = m0 + wm + mt * 16 + quad * 4 + r;
                float val = acc[mt][nt][r] + bv;
                if (MODE == 0) {
                    ushort_t* ws = (ushort_t*)out_;
                    const int which = n >> 10;
                    if (which == 0) val *= C1;
                    const size_t pl = (which == 2) ? 3 : which;
                    const int cc = n & 1023;
                    const int h = cc >> 6, d = cc & 63;
                    const int b = m >> 10, t = m & 1023;
                    ws[pl * PLANE + ((size_t)(b * NHEAD + h) * T_SEQ + t) * HDIM + d] = f2bf(val);
                } else {
                    ((float*)out_)[(size_t)m * Ndim + n] = val;
                }
            }
        }
}

// ---------------------------------------------------------------------------
// Flash attention. Grid (8,64) = 512 blocks; block bx does i-tiles
// {15-bx, bx} sequentially -> UNIFORM 17 j-tiles/block (no tail).
// Staging AFTER S1: load -> immediate ds_write_b128 (no barrier-crossing
// registers => no spill). XOR-chunk-swizzled rows (slot idx holds chunk
// (idx&7)^(row&7) of row idx>>3) -> conflict-free b128 frag reads.
// Ps: bf16 skew [il][jl] stride 68 (2-way free). Probs alias Es rows [0,64).
// q & E pre-scaled by C1. LDS ~41.7 KB.
// ---------------------------------------------------------------------------
__global__ __launch_bounds__(256) void flash_attn(
    const ushort_t* __restrict__ qp, const ushort_t* __restrict__ kp,
    const ushort_t* __restrict__ vTp, const ushort_t* __restrict__ E16,
    ushort_t* __restrict__ y16)
{
    __shared__ __align__(16) ushort_t Ks[64 * 64];
    __shared__ __align__(16) ushort_t Vt[64 * 64];
    __shared__ __align__(16) ushort_t Es[128 * 64];   // rows [0,64) alias probs
    __shared__ __align__(16) ushort_t Ps[65 * 68];    // row 64 = dump

    const int bx = (int)blockIdx.x;
    const int bh = blockIdx.y;
    const int h = bh & (NHEAD - 1);
    const int b = bh >> 4;
    const int tid = threadIdx.x;
    const int w = tid >> 6;
    const int lane = tid & 63;
    const int l15 = lane & 15;
    const int quad = lane >> 4;

    const size_t base = (size_t)bh * T_SEQ * HDIM;
    const ushort_t* Eh = E16 + (size_t)h * T_SEQ * HDIM;
    const ushort_t* vTb = vTp + (size_t)bh * 65536;

    bf16x8 ones;
#pragma unroll
    for (int i = 0; i < 8; i++) ones[i] = (__bf16)1.0f;

    const int xsw = l15 & 7;

#pragma unroll 1
    for (int ph = 0; ph < 2; ph++) {
        const int it = ph ? bx : 15 - bx;
        const int i0 = it * 64;

        // Q A-fragments from global (q pre-scaled by C1)
        bf16x8 qf[2];
        {
            const ushort_t* qrow = qp + base + (size_t)(i0 + w * 16 + l15) * HDIM;
            qf[0] = *reinterpret_cast<const bf16x8*>(qrow + quad * 8);
            qf[1] = *reinterpret_cast<const bf16x8*>(qrow + 32 + quad * 8);
        }

        f32x4 o[4], o5;
#pragma unroll
        for (int dt = 0; dt < 4; dt++) o[dt] = (f32x4){0.f, 0.f, 0.f, 0.f};
        o5 = (f32x4){0.f, 0.f, 0.f, 0.f};
        float mrow[4];
#pragma unroll
        for (int r = 0; r < 4; r++) mrow[r] = -3e38f;

        for (int j0 = 0; j0 <= i0; j0 += 64) {
            const int d0 = i0 - j0;

            __syncthreads();   // S1: prev tile's LDS readers done
            // ---- stage K/V/E: load -> immediate ds_write (no barrier crossing) ----
#pragma unroll
            for (int t = 0; t < 2; t++) {
                const int idx = tid + t * 256;
                const int row = idx >> 3;
                const int g = (idx & 7) ^ (row & 7);
                const uint4 kv = *reinterpret_cast<const uint4*>(
                    kp + base + (size_t)(j0 + row) * HDIM + g * 8);
                *reinterpret_cast<uint4*>(&Ks[(size_t)idx * 8]) = kv;
                const uint4 vv = *reinterpret_cast<const uint4*>(
                    vTb + (size_t)row * T_SEQ + j0 + g * 8);
                *reinterpret_cast<uint4*>(&Vt[(size_t)idx * 8]) = vv;
            }
#pragma unroll
            for (int t = 0; t < 4; t++) {
                const int idx = tid + t * 256;
                const int row = idx >> 3;
                const int g = (idx & 7) ^ (row & 7);
                int gr = d0 - 64 + row;
                if (gr < 0) gr = 0;
                const uint4 ev = *reinterpret_cast<const uint4*>(
                    Eh + (size_t)gr * HDIM + g * 8);
                *reinterpret_cast<uint4*>(&Es[(size_t)idx * 8]) = ev;
            }
            __syncthreads();   // S2

            // ---- phase 1: S = Q@K^T ; P band = E@K^T ----
            f32x4 s[4], pb[2][4];
#pragma unroll
            for (int nt = 0; nt < 4; nt++) {
                s[nt] = (f32x4){0.f, 0.f, 0.f, 0.f};
                pb[0][nt] = (f32x4){0.f, 0.f, 0.f, 0.f};
                pb[1][nt] = (f32x4){0.f, 0.f, 0.f, 0.f};
            }
#pragma unroll
            for (int ks = 0; ks < 2; ks++) {
                const int cidx = (ks * 4 + quad) ^ xsw;
                const bf16x8 ae0 = *reinterpret_cast<const bf16x8*>(&Es[((w * 32 + l15) * 8 + cidx) * 8]);
                const bf16x8 ae1 = *reinterpret_cast<const bf16x8*>(&Es[((w * 32 + 16 + l15) * 8 + cidx) * 8]);
#pragma unroll
                for (int nt = 0; nt < 4; nt++) {
                    const bf16x8 bk = *reinterpret_cast<const bf16x8*>(&Ks[((nt * 16 + l15) * 8 + cidx) * 8]);
                    s[nt] = __builtin_amdgcn_mfma_f32_16x16x32_bf16(qf[ks], bk, s[nt], 0, 0, 0);
                    pb[0][nt] = __builtin_amdgcn_mfma_f32_16x16x32_bf16(ae0, bk, pb[0][nt], 0, 0, 0);
                    pb[1][nt] = __builtin_amdgcn_mfma_f32_16x16x32_bf16(ae1, bk, pb[1][nt], 0, 0, 0);
                }
            }
            // skew store: Ps[il_t][jl] stride 68; OOB -> dump row 64
#pragma unroll
            for (int mf = 0; mf < 2; mf++)
#pragma unroll
                for (int nt = 0; nt < 4; nt++) {
                    const int jl = nt * 16 + l15;
#pragma unroll
                    for (int r = 0; r < 4; r++) {
                        const int br = w * 32 + mf * 16 + quad * 4 + r;
                        const int il_t = br - 64 + jl;
                        const int addr = ((unsigned)il_t < 64u) ? il_t * 68 + jl : 64 * 68 + jl;
                        Ps[addr] = f2bf(pb[mf][nt][r]);
                    }
                }
            __syncthreads();   // S3

            // ---- gather + online softmax (log2 domain) ----
            float pv[4][4], mnew[4];
#pragma unroll
            for (int r = 0; r < 4; r++) mnew[r] = mrow[r];
            const int il0 = w * 16 + quad * 4;
            if (j0 < i0) {
#pragma unroll
                for (int nt = 0; nt < 4; nt++) {
                    const int jl = nt * 16 + l15;
#pragma unroll
                    for (int r = 0; r < 4; r++) {
                        const float sv = s[nt][r] + bf2f(Ps[(il0 + r) * 68 + jl]);
                        pv[nt][r] = sv;
                        mnew[r] = fmaxf(mnew[r], sv);
                    }
                }
            } else {
#pragma unroll
                for (int nt = 0; nt < 4; nt++) {
                    const int jl = nt * 16 + l15;
#pragma unroll
                    for (int r = 0; r < 4; r++) {
                        const int il = il0 + r;
                        float sv = s[nt][r] + bf2f(Ps[il * 68 + jl]);
                        if (jl > il) sv = -3e38f;
                        pv[nt][r] = sv;
                        mnew[r] = fmaxf(mnew[r], sv);
                    }
                }
            }
#pragma unroll
            for (int r = 0; r < 4; r++)
#pragma unroll
                for (int off = 1; off < 16; off <<= 1)
                    mnew[r] = fmaxf(mnew[r], __shfl_xor(mnew[r], off, 64));
            float alpha[4];
#pragma unroll
            for (int r = 0; r < 4; r++) {
                alpha[r] = exp2f(mrow[r] - mnew[r]);
                mrow[r] = mnew[r];
            }
#pragma unroll
            for (int nt = 0; nt < 4; nt++)
#pragma unroll
                for (int r = 0; r < 4; r++)
                    pv[nt][r] = exp2f(pv[nt][r] - mnew[r]);
#pragma unroll
            for (int dt = 0; dt < 4; dt++)
#pragma unroll
                for (int r = 0; r < 4; r++) o[dt][r] *= alpha[r];
#pragma unroll
            for (int r = 0; r < 4; r++) o5[r] *= alpha[r];
            // probs -> Es rows [0,64), swizzled chunks (free after phase-1 reads)
#pragma unroll
            for (int nt = 0; nt < 4; nt++) {
                const int jl = nt * 16 + l15;
#pragma unroll
                for (int r = 0; r < 4; r++) {
                    const int row = il0 + r;
                    Es[(row * 8 + ((jl >> 3) ^ (row & 7))) * 8 + (jl & 7)] = f2bf(pv[nt][r]);
                }
            }
            __syncthreads();   // S4

            // ---- O += P @ V ; denominator via ones column ----
#pragma unroll
            for (int ks = 0; ks < 2; ks++) {
                const int cidx = (ks * 4 + quad) ^ xsw;
                const bf16x8 ap = *reinterpret_cast<const bf16x8*>(&Es[((w * 16 + l15) * 8 + cidx) * 8]);
#pragma unroll
                for (int dt = 0; dt < 4; dt++) {
                    const bf16x8 bv = *reinterpret_cast<const bf16x8*>(&Vt[((dt * 16 + l15) * 8 + cidx) * 8]);
                    o[dt] = __builtin_amdgcn_mfma_f32_16x16x32_bf16(ap, bv, o[dt], 0, 0, 0);
                }
                o5 = __builtin_amdgcn_mfma_f32_16x16x32_bf16(ap, ones, o5, 0, 0, 0);
            }
        }

        // ---- epilogue ----
        float inv[4];
#pragma unroll
        for (int r = 0; r < 4; r++) inv[r] = 1.0f / o5[r];
#pragma unroll
        for (int dt = 0; dt < 4; dt++)
#pragma unroll
            for (int r = 0; r < 4; r++) {
                const int il = w * 16 + quad * 4 + r;
                const int d = dt * 16 + l15;
                y16[((size_t)(b * T_SEQ + i0 + il)) * 1024 + h * 64 + d] = f2bf(o[dt][r] * inv[r]);
            }
    }
}

extern "C" void kernel_launch(void* const* d_in, const int* in_sizes, int n_in,
                              void* d_out, int out_size, void* d_ws, size_t ws_size,
                              hipStream_t stream) {
    float* out = (float*)d_out;

    const void* x = nullptr; const void* Wa = nullptr; const void* ba = nullptr;
    const void* Wp = nullptr; const void* bp = nullptr; const void* E = nullptr;
    int anomaly = 0;
    if (n_in != 6) {
        anomaly = 2;
    } else {
        int c1M = 0;
        for (int i = 0; i < 6; i++) {
            const int s = in_sizes[i];
            if      (s == 4194304) x  = d_in[i];
            else if (s == 3145728) Wa = d_in[i];
            else if (s == 3072)    ba = d_in[i];
            else if (s == 1024)    bp = d_in[i];
            else if (s == 1048576) { if (c1M == 0) Wp = d_in[i]; else E = d_in[i]; c1M++; }
            else anomaly = 1;
        }
        if (!x || !Wa || !ba || !Wp || !bp || !E || c1M != 2) anomaly = 1;
    }
    if (!anomaly && out_size != 4194304) anomaly = 3;
    if (!anomaly && ws_size < (size_t)52428800) anomaly = 4;
    if (anomaly) {
        sentinel_kernel<<<(out_size + 255) / 256, 256, 0, stream>>>(out, out_size, 1000.0f * anomaly);
        return;
    }

    ushort_t* ws   = (ushort_t*)d_ws;
    ushort_t* qp   = ws;
    ushort_t* kp   = ws + (size_t)PLANE;
    ushort_t* vTp  = ws + (size_t)2 * PLANE;
    ushort_t* vtmp = ws + (size_t)3 * PLANE;
    ushort_t* y16  = vtmp;
    ushort_t* x16  = ws + (size_t)4 * PLANE;
    ushort_t* WaT  = ws + (size_t)5 * PLANE;
    ushort_t* WpT  = WaT + (size_t)3145728;
    ushort_t* E16  = WpT + (size_t)1048576;

    prep_fused<<<6144, 256, 0, stream>>>(
        (const float*)x, x16, (const float*)E, E16,
        (const float*)Wa, WaT, (const float*)Wp, WpT);

    gemm128<0><<<dim3(24, 32), 256, 0, stream>>>(x16, WaT, (const float*)ba, (void*)ws, 3072, 1024);

    transpose_v<<<dim3(16, 64), 256, 0, stream>>>(vtmp, vTp);

    flash_attn<<<dim3(8, 64), 256, 0, stream>>>(qp, kp, vTp, E16, y16);

    gemm128<1><<<dim3(8, 32), 256, 0, stream>>>(y16, WpT, (const float*)bp, (void*)out, 1024, 1024);
}